// Round 1
// baseline (301.043 us; speedup 1.0000x reference)
//
#include <hip/hip_runtime.h>
#include <hip/hip_bf16.h>

#define DIN 256
#define DOUT 128
#define NB 64

using short8  = __attribute__((ext_vector_type(8))) short;
using floatx4 = __attribute__((ext_vector_type(4))) float;

__device__ __forceinline__ unsigned short f2bf(float f) {
    union { float f; unsigned u; } x; x.f = f;
    unsigned u = x.u;
    unsigned r = u + 0x7fffu + ((u >> 16) & 1u);   // round-to-nearest-even
    return (unsigned short)(r >> 16);
}

// d_ws layout: W0T[c][k] = bf16(W0[k][c]),  [128][256] bf16 = 64 KB
__global__ void w0_transpose_kernel(const float* __restrict__ W0,
                                    unsigned short* __restrict__ W0T) {
    int e = blockIdx.x * blockDim.x + threadIdx.x;   // 32768 elements
    int c = e & (DOUT - 1);
    int k = e >> 7;
    W0T[c * DIN + k] = f2bf(W0[k * DOUT + c]);
}

__global__ __launch_bounds__(512) void fused_embed_kernel(
    const float* __restrict__ feat0,
    const float* __restrict__ emb_table,
    const unsigned short* __restrict__ W0T,
    const int* __restrict__ node_ids,
    const int* __restrict__ node_tids,
    const int* __restrict__ type_ids,
    float* __restrict__ out,
    int n)
{
    __shared__ unsigned short sA[NB * DIN];   // 32 KB, XOR-swizzled rows
    __shared__ unsigned char  sFeat[NB];

    const int t    = threadIdx.x;
    const int base = blockIdx.x * NB;

    // ---------- staging phase: 8 threads per node ----------
    {
        const int m = t >> 3;      // node in tile, 0..63
        const int p = t & 7;       // part, 0..7
        const int i = base + m;
        int tid = 1;
        if (i < n) tid = node_tids[i];
        const bool featured = (i < n) && (tid == 0);
        if (p == 0) sFeat[m] = featured ? 1 : 0;

        if (featured) {
            const float* src = feat0 + (long long)type_ids[i] * DIN;
            #pragma unroll
            for (int j = 0; j < 8; ++j) {
                const int k = j * 32 + p * 4;              // coalesced 128B/8 lanes
                const float4 v = *reinterpret_cast<const float4*>(src + k);
                ushort4 pk;
                pk.x = f2bf(v.x); pk.y = f2bf(v.y);
                pk.z = f2bf(v.z); pk.w = f2bf(v.w);
                const unsigned addr =
                    (unsigned)(m * 512 + k * 2) ^ ((unsigned)(m & 7) << 4);
                *reinterpret_cast<ushort4*>(reinterpret_cast<char*>(sA) + addr) = pk;
            }
        } else if (i < n) {
            // featureless: direct row copy emb_table[node_ids[i]] -> out[i]
            const float4* src = reinterpret_cast<const float4*>(
                emb_table + (long long)node_ids[i] * DOUT);
            float4* dst = reinterpret_cast<float4*>(out + (long long)i * DOUT);
            #pragma unroll
            for (int j = 0; j < 4; ++j) dst[p + j * 8] = src[p + j * 8];
        }
    }
    __syncthreads();

    // ---------- MFMA phase: 8 waves = 4 row-tiles x 2 col-halves ----------
    const int w  = t >> 6;       // wave 0..7
    const int l  = t & 63;
    const int rt = w >> 1;       // row tile (16 rows)
    const int h  = w & 1;        // col half (64 cols)
    const int lr = l & 15;
    const int kg = l >> 4;       // 0..3

    floatx4 acc[4];
    #pragma unroll
    for (int ct = 0; ct < 4; ++ct) acc[ct] = (floatx4){0.f, 0.f, 0.f, 0.f};

    const int row = rt * 16 + lr;
    const unsigned rowbase = (unsigned)(row * 512);
    const unsigned rswz    = (unsigned)(row & 7) << 4;

    #pragma unroll
    for (int ks = 0; ks < 8; ++ks) {
        const unsigned aaddr = (rowbase + (unsigned)(ks * 64 + kg * 16)) ^ rswz;
        const short8 af = *reinterpret_cast<const short8*>(
            reinterpret_cast<const char*>(sA) + aaddr);
        const int kelem = ks * 32 + kg * 8;
        #pragma unroll
        for (int ct = 0; ct < 4; ++ct) {
            const int col = h * 64 + ct * 16 + lr;
            const short8 bf = *reinterpret_cast<const short8*>(W0T + col * DIN + kelem);
            acc[ct] = __builtin_amdgcn_mfma_f32_16x16x32_bf16(af, bf, acc[ct], 0, 0, 0);
        }
    }

    // ---------- epilogue: predicated store of projected rows ----------
    bool ok[4];
    int  orow[4];
    #pragma unroll
    for (int r = 0; r < 4; ++r) {
        orow[r] = rt * 16 + kg * 4 + r;          // D row = (lane>>4)*4 + reg
        ok[r]   = sFeat[orow[r]] != 0;
    }
    #pragma unroll
    for (int ct = 0; ct < 4; ++ct) {
        const int col = h * 64 + ct * 16 + lr;   // D col = lane&15
        #pragma unroll
        for (int r = 0; r < 4; ++r) {
            if (ok[r])
                out[(long long)(base + orow[r]) * DOUT + col] = acc[ct][r];
        }
    }
}

extern "C" void kernel_launch(void* const* d_in, const int* in_sizes, int n_in,
                              void* d_out, int out_size, void* d_ws, size_t ws_size,
                              hipStream_t stream) {
    const float* feat0      = (const float*)d_in[0];
    const float* W0         = (const float*)d_in[1];
    const float* emb_table  = (const float*)d_in[2];
    const int*   node_ids   = (const int*)d_in[3];
    const int*   node_tids  = (const int*)d_in[4];
    const int*   type_ids   = (const int*)d_in[5];
    float*       out        = (float*)d_out;
    const int n = in_sizes[3];                      // N = 500000

    unsigned short* W0T = (unsigned short*)d_ws;    // 64 KB in workspace

    hipLaunchKernelGGL(w0_transpose_kernel, dim3((DIN * DOUT) / 256), dim3(256),
                       0, stream, W0, W0T);

    const int grid = (n + NB - 1) / NB;
    hipLaunchKernelGGL(fused_embed_kernel, dim3(grid), dim3(512), 0, stream,
                       feat0, emb_table, W0T, node_ids, node_tids, type_ids, out, n);
}

// Round 2
// 158.929 us; speedup vs baseline: 1.8942x; 1.8942x over previous
//
#include <hip/hip_runtime.h>
#include <hip/hip_bf16.h>

#define DIN 256
#define DOUT 128
#define NB 64

using short8  = __attribute__((ext_vector_type(8))) short;
using floatx4 = __attribute__((ext_vector_type(4))) float;

__device__ __forceinline__ unsigned short f2bf(float f) {
    union { float f; unsigned u; } x; x.f = f;
    unsigned u = x.u;
    unsigned r = u + 0x7fffu + ((u >> 16) & 1u);   // round-to-nearest-even
    return (unsigned short)(r >> 16);
}

// d_ws layout: Bfrag in MFMA-fragment order, lane-major (fully coalesced):
//   Bfrag[((wt*8 + ks)*64 + lane)*8 + j] = bf16(W0[(ks*32 + (lane>>4)*8 + j)][wt*16 + (lane&15)])
// 8 col-tiles x 8 ks x 64 lanes x 8 shorts = 64 KB
__global__ void w0_pack_kernel(const float* __restrict__ W0,
                               unsigned short* __restrict__ Bfrag) {
    int e = blockIdx.x * blockDim.x + threadIdx.x;   // 32768 elements
    int j  = e & 7;
    int l  = (e >> 3) & 63;
    int ks = (e >> 9) & 7;
    int wt = e >> 12;
    int k = ks * 32 + (l >> 4) * 8 + j;
    int c = wt * 16 + (l & 15);
    Bfrag[e] = f2bf(W0[k * DOUT + c]);
}

__global__ __launch_bounds__(512) void fused_embed_kernel(
    const float* __restrict__ feat0,
    const float* __restrict__ emb_table,
    const unsigned short* __restrict__ Bfrag,
    const int* __restrict__ node_ids,
    const int* __restrict__ node_tids,
    const int* __restrict__ type_ids,
    float* __restrict__ out,
    int n)
{
    __shared__ unsigned short sA[NB * DIN];   // 32 KB, XOR-swizzled rows
    __shared__ unsigned char  sFeat[NB];

    const int t    = threadIdx.x;
    const int base = blockIdx.x * NB;
    const int w    = t >> 6;      // wave 0..7 = col tile
    const int l    = t & 63;

    // ---------- hoist B fragments into registers (coalesced, L2-resident) ----
    short8 bf[8];
    {
        const short8* bsrc = reinterpret_cast<const short8*>(Bfrag);
        #pragma unroll
        for (int ks = 0; ks < 8; ++ks)
            bf[ks] = bsrc[(w * 8 + ks) * 64 + l];
    }

    // ---------- staging phase: 8 threads per node ----------
    {
        const int m = t >> 3;      // node in tile, 0..63
        const int p = t & 7;       // part, 0..7
        const int i = base + m;
        int tid = 1;
        if (i < n) tid = node_tids[i];
        const bool featured = (i < n) && (tid == 0);
        if (p == 0) sFeat[m] = featured ? 1 : 0;

        if (featured) {
            const float* src = feat0 + (long long)type_ids[i] * DIN;
            float4 v[8];
            #pragma unroll
            for (int j = 0; j < 8; ++j)   // 8 independent loads in flight
                v[j] = *reinterpret_cast<const float4*>(src + j * 32 + p * 4);
            #pragma unroll
            for (int j = 0; j < 8; ++j) {
                const int k = j * 32 + p * 4;
                ushort4 pk;
                pk.x = f2bf(v[j].x); pk.y = f2bf(v[j].y);
                pk.z = f2bf(v[j].z); pk.w = f2bf(v[j].w);
                const unsigned addr =
                    (unsigned)(m * 512 + k * 2) ^ ((unsigned)(m & 7) << 4);
                *reinterpret_cast<ushort4*>(reinterpret_cast<char*>(sA) + addr) = pk;
            }
        } else if (i < n) {
            // featureless: direct row copy emb_table[node_ids[i]] -> out[i]
            const float4* src = reinterpret_cast<const float4*>(
                emb_table + (long long)node_ids[i] * DOUT);
            float4* dst = reinterpret_cast<float4*>(out + (long long)i * DOUT);
            float4 v[4];
            #pragma unroll
            for (int j = 0; j < 4; ++j) v[j] = src[p + j * 8];
            #pragma unroll
            for (int j = 0; j < 4; ++j) dst[p + j * 8] = v[j];
        }
    }
    __syncthreads();

    // ---------- MFMA phase: wave w -> cols [w*16, w*16+16), all 64 rows -----
    const int lr = l & 15;
    const int kg = l >> 4;        // 0..3

    floatx4 acc[4];
    #pragma unroll
    for (int rt = 0; rt < 4; ++rt) acc[rt] = (floatx4){0.f, 0.f, 0.f, 0.f};

    #pragma unroll
    for (int ks = 0; ks < 8; ++ks) {
        #pragma unroll
        for (int rt = 0; rt < 4; ++rt) {      // 4 independent acc chains
            const int row = rt * 16 + lr;
            const unsigned aaddr =
                (unsigned)(row * 512 + ks * 64 + kg * 16) ^ ((unsigned)(row & 7) << 4);
            const short8 af = *reinterpret_cast<const short8*>(
                reinterpret_cast<const char*>(sA) + aaddr);
            acc[rt] = __builtin_amdgcn_mfma_f32_16x16x32_bf16(af, bf[ks], acc[rt], 0, 0, 0);
        }
    }

    // ---------- epilogue: predicated store of projected rows ----------
    const int col = w * 16 + lr;
    #pragma unroll
    for (int rt = 0; rt < 4; ++rt) {
        #pragma unroll
        for (int r = 0; r < 4; ++r) {
            const int row = rt * 16 + kg * 4 + r;   // D row = (lane>>4)*4 + reg
            if (sFeat[row])
                out[(long long)(base + row) * DOUT + col] = acc[rt][r];
        }
    }
}

extern "C" void kernel_launch(void* const* d_in, const int* in_sizes, int n_in,
                              void* d_out, int out_size, void* d_ws, size_t ws_size,
                              hipStream_t stream) {
    const float* feat0      = (const float*)d_in[0];
    const float* W0         = (const float*)d_in[1];
    const float* emb_table  = (const float*)d_in[2];
    const int*   node_ids   = (const int*)d_in[3];
    const int*   node_tids  = (const int*)d_in[4];
    const int*   type_ids   = (const int*)d_in[5];
    float*       out        = (float*)d_out;
    const int n = in_sizes[3];                      // N = 500000

    unsigned short* Bfrag = (unsigned short*)d_ws;  // 64 KB in workspace

    hipLaunchKernelGGL(w0_pack_kernel, dim3((DIN * DOUT) / 256), dim3(256),
                       0, stream, W0, Bfrag);

    const int grid = (n + NB - 1) / NB;
    hipLaunchKernelGGL(fused_embed_kernel, dim3(grid), dim3(512), 0, stream,
                       feat0, emb_table, Bfrag, node_ids, node_tids, type_ids, out, n);
}